// Round 4
// baseline (335.292 us; speedup 1.0000x reference)
//
#include <hip/hip_runtime.h>

typedef unsigned short u16;
typedef unsigned int u32;
typedef __attribute__((ext_vector_type(8))) short bf16x8;
typedef __attribute__((ext_vector_type(4))) float f32x4;
typedef __attribute__((ext_vector_type(4))) unsigned short u16x4;

#define NKV 144   // 128 V-dims + 1 ones-row (Ksum) + 15 zero pad (9 MFMA n-frags)

__device__ __forceinline__ u16 f2b(float f){
  u32 i = __float_as_uint(f);
  u32 r = (i + 0x7FFFu + ((i >> 16) & 1u)) >> 16;
  return (u16)r;
}

__device__ __forceinline__ void cp16(const void* g, void* l){
  __builtin_amdgcn_global_load_lds(
      (__attribute__((address_space(1))) void*)(const_cast<void*>(g)),
      (__attribute__((address_space(3))) void*)(l), 16, 0, 0);
}

// Stage rows x 64 bf16 (rows*128 bytes) into LDS. Linear LDS dest (required by
// global_load_lds); XOR 16B-chunk swizzle applied on the GLOBAL source so that
// swizzled reads below are conflict-light (2-way max).
__device__ __forceinline__ void stage_tile(const u16* g, int stride_el, int rows,
                                           u16* lds, int tid){
  const char* gc = (const char*)g;
  char* lc = (char*)lds;
  const int total = rows * 128;
  for (int off = tid * 16; off < total; off += 4096){
    int row = off >> 7;
    int chunk = (off >> 4) & 7;
    int gchunk = chunk ^ (row & 7);
    cp16(gc + (size_t)row * (size_t)(stride_el * 2) + gchunk * 16, lc + off);
  }
}

// Fragment read: logical (row, k-chunk) -> swizzled physical chunk.
__device__ __forceinline__ bf16x8 frag_ld(const u16* lds, int row, int kk, int lane){
  int chunk = (kk >> 3) + (lane >> 4);
  int pc = chunk ^ (row & 7);
  return *(const bf16x8*)(lds + row * 64 + pc * 8);
}

// ---- core A: 4 waves in 2x2, each wave 64x64 (4x4 frags), BM=BN=128, BK=64 ----
__device__ __forceinline__ void core22(const u16* Ag, int As, const u16* Bg, int Bs,
                                       int ksteps, u16* ldsA, u16* ldsB,
                                       f32x4 (&acc)[4][4]){
  const int tid = threadIdx.x, lane = tid & 63, w = tid >> 6;
  const int wm = (w >> 1) * 64, wn = (w & 1) * 64;
  for (int t = 0; t < ksteps; ++t){
    stage_tile(Ag + t * 64, As, 128, ldsA, tid);
    stage_tile(Bg + t * 64, Bs, 128, ldsB, tid);
    __syncthreads();
#pragma unroll
    for (int kk = 0; kk < 64; kk += 32){
      bf16x8 af[4], bfr[4];
#pragma unroll
      for (int i = 0; i < 4; ++i) af[i]  = frag_ld(ldsA, wm + i * 16 + (lane & 15), kk, lane);
#pragma unroll
      for (int i = 0; i < 4; ++i) bfr[i] = frag_ld(ldsB, wn + i * 16 + (lane & 15), kk, lane);
#pragma unroll
      for (int m = 0; m < 4; ++m)
#pragma unroll
        for (int n = 0; n < 4; ++n)
          acc[m][n] = __builtin_amdgcn_mfma_f32_16x16x32_bf16(af[m], bfr[n], acc[m][n], 0, 0, 0);
    }
    __syncthreads();
  }
}

// ---- core B: 4 waves m-stacked, each wave 32x144 (2x9 frags), BM=128, BN=144 ----
__device__ __forceinline__ void core41(const u16* Ag, int As, const u16* Bg, int Bs,
                                       int ksteps, u16* ldsA, u16* ldsB,
                                       f32x4 (&acc)[2][9]){
  const int tid = threadIdx.x, lane = tid & 63, w = tid >> 6;
  const int wm = w * 32;
  for (int t = 0; t < ksteps; ++t){
    stage_tile(Ag + t * 64, As, 128, ldsA, tid);
    stage_tile(Bg + t * 64, Bs, NKV, ldsB, tid);
    __syncthreads();
#pragma unroll
    for (int kk = 0; kk < 64; kk += 32){
      bf16x8 af[2], bfr[9];
#pragma unroll
      for (int i = 0; i < 2; ++i) af[i]  = frag_ld(ldsA, wm + i * 16 + (lane & 15), kk, lane);
#pragma unroll
      for (int i = 0; i < 9; ++i) bfr[i] = frag_ld(ldsB, i * 16 + (lane & 15), kk, lane);
#pragma unroll
      for (int m = 0; m < 2; ++m)
#pragma unroll
        for (int n = 0; n < 9; ++n)
          acc[m][n] = __builtin_amdgcn_mfma_f32_16x16x32_bf16(af[m], bfr[n], acc[m][n], 0, 0, 0);
    }
    __syncthreads();
  }
}

// ---- prep: x cast (blocks 0..2047) + VT pad-row init (blocks 2048..2303) ----
__global__ void k_cast2(const float* __restrict__ src, u16* __restrict__ dst,
                        u16* __restrict__ VT){
  if (blockIdx.x < 2048){
    const int n4 = 16384 * 1024 / 4;
    const int stride = 2048 * 256;
    for (int i = blockIdx.x * 256 + threadIdx.x; i < n4; i += stride){
      float4 v = ((const float4*)src)[i];
      u16x4 o; o[0] = f2b(v.x); o[1] = f2b(v.y); o[2] = f2b(v.z); o[3] = f2b(v.w);
      ((u16x4*)dst)[i] = o;
    }
  } else {
    const int total = 32 * 16 * 4096 / 4;
    const int stride = 256 * 256;
    for (int i = (blockIdx.x - 2048) * 256 + threadIdx.x; i < total; i += stride){
      int idx = i * 4;
      int s   = idx & 4095;
      int rem = idx >> 12;
      int row = 128 + (rem & 15);
      int bh  = rem >> 4;
      u16 val = (row == 128) ? (u16)0x3F80 : (u16)0;
      u16x4 o = {val, val, val, val};
      *(u16x4*)&VT[((size_t)bh * NKV + row) * 4096 + s] = o;
    }
  }
}

// dst[C][R] bf16 = transpose(src[R][C] f32) -- used for omega only
__global__ void k_tc(const float* __restrict__ src, u16* __restrict__ dst, int R, int C){
  __shared__ float t[64][65];
  const int c0 = blockIdx.x * 64, r0 = blockIdx.y * 64;
  const int tid = threadIdx.x;
  for (int i = tid; i < 4096; i += 256){
    int r = i >> 6, c = i & 63;
    t[r][c] = src[(size_t)(r0 + r) * C + c0 + c];
  }
  __syncthreads();
  for (int i = tid; i < 4096; i += 256){
    int r = i >> 6, c = i & 63;
    dst[(size_t)(c0 + r) * R + r0 + c] = f2b(t[c][r]);
  }
}

// 4 weight transposes in one launch: grid (16,16,4)
__global__ void k_tc4(const float* __restrict__ Wq, const float* __restrict__ Wk,
                      const float* __restrict__ Wv, const float* __restrict__ Wo,
                      u16* __restrict__ WqT, u16* __restrict__ WkT,
                      u16* __restrict__ WvT, u16* __restrict__ WoT){
  __shared__ float t[64][65];
  const int z = blockIdx.z;
  const float* src = z == 0 ? Wq : (z == 1 ? Wk : (z == 2 ? Wv : Wo));
  u16* dst = z == 0 ? WqT : (z == 1 ? WkT : (z == 2 ? WvT : WoT));
  const int c0 = blockIdx.x * 64, r0 = blockIdx.y * 64;
  const int tid = threadIdx.x;
  for (int i = tid; i < 4096; i += 256){
    int r = i >> 6, c = i & 63;
    t[r][c] = src[(size_t)(r0 + r) * 1024 + c0 + c];
  }
  __syncthreads();
  for (int i = tid; i < 4096; i += 256){
    int r = i >> 6, c = i & 63;
    dst[(size_t)(c0 + r) * 1024 + r0 + c] = f2b(t[c][r]);
  }
}

// ---- K2: QKV projection with FUSED phi. grid (128 mtiles, 24 ntiles) ----
// sect 0 (Q): zp = (Q+bq)@omega in-kernel -> Qf (sin||cos, row-major)
// sect 1 (K): same -> KfT (transposed [f][s])
// sect 2 (V): bias + transposed store to VT
__global__ __launch_bounds__(256, 2)
void k_qkv(const u16* __restrict__ xb, const u16* __restrict__ WqT,
           const u16* __restrict__ WkT, const u16* __restrict__ WvT,
           const float* __restrict__ bq, const float* __restrict__ bk,
           const float* __restrict__ bv, const u16* __restrict__ wT,
           u16* __restrict__ Qf, u16* __restrict__ KfT, u16* __restrict__ VT){
  __shared__ u16 lds[16384];            // 32 KiB total, reused by phi stage
  u16* ldsA = lds;
  u16* ldsB = lds + 8192;
  const int mtile = blockIdx.x, ntile = blockIdx.y;
  const int sect = ntile >> 3, h = ntile & 7;
  const u16* Ag = xb + (size_t)mtile * 128 * 1024;
  const u16* WT = sect == 0 ? WqT : (sect == 1 ? WkT : WvT);
  const u16* Bg = WT + (size_t)h * 128 * 1024;
  f32x4 acc[4][4];
#pragma unroll
  for (int m = 0; m < 4; ++m)
#pragma unroll
    for (int n = 0; n < 4; ++n) acc[m][n] = f32x4{0.f, 0.f, 0.f, 0.f};
  core22(Ag, 1024, Bg, 1024, 16, ldsA, ldsB, acc);

  const int tid = threadIdx.x, lane = tid & 63, w = tid >> 6;
  const int wm = (w >> 1) * 64, wn = (w & 1) * 64;
  const int b  = (mtile * 128) >> 12;
  const int s0 = (mtile * 128) & 4095;
  const int bh = b * 8 + h;

  if (sect == 2){
    const float* bias = bv + h * 128;
#pragma unroll
    for (int m = 0; m < 4; ++m){
      const int r0 = wm + m * 16 + ((lane >> 4) << 2);
#pragma unroll
      for (int n = 0; n < 4; ++n){
        const int col = wn + n * 16 + (lane & 15);
        const float bc = bias[col];
        u16x4 pk;
#pragma unroll
        for (int j = 0; j < 4; ++j) pk[j] = f2b(acc[m][n][j] + bc);
        *(u16x4*)&VT[((size_t)bh * NKV + col) * 4096 + s0 + r0] = pk;
      }
    }
    return;
  }

  // ---- fused phi: zp = bf16(Q+bias) @ omega (2 K-steps of 64, LDS reused) ----
  const float* bias = (sect == 0 ? bq : bk) + h * 128;
  u16x4 qv[4][4];                       // packed bf16 Q-tile values (frees acc)
#pragma unroll
  for (int m = 0; m < 4; ++m)
#pragma unroll
    for (int n = 0; n < 4; ++n){
      const float bc = bias[wn + n * 16 + (lane & 15)];
      u16x4 p;
#pragma unroll
      for (int j = 0; j < 4; ++j) p[j] = f2b(acc[m][n][j] + bc);
      qv[m][n] = p;
    }
  const int myStep = wn >> 6;           // waves with wn=0 hold k<64, wn=64 hold k>=64
  f32x4 acc2[4][4];
#pragma unroll
  for (int m = 0; m < 4; ++m)
#pragma unroll
    for (int n = 0; n < 4; ++n) acc2[m][n] = f32x4{0.f, 0.f, 0.f, 0.f};
#pragma unroll
  for (int s = 0; s < 2; ++s){
    stage_tile(wT + s * 64, 128, 128, ldsB, tid);   // omega^T K-step s
    if (myStep == s){
#pragma unroll
      for (int m = 0; m < 4; ++m)
#pragma unroll
        for (int n = 0; n < 4; ++n)
#pragma unroll
          for (int j = 0; j < 4; ++j){
            int row = wm + m * 16 + ((lane >> 4) << 2) + j;
            int c   = n * 16 + (lane & 15);         // k-pos within the step
            ldsA[row * 64 + (((c >> 3) ^ (row & 7)) << 3) + (c & 7)] = qv[m][n][j];
          }
    }
    __syncthreads();
#pragma unroll
    for (int kk = 0; kk < 64; kk += 32){
      bf16x8 af[4], bfr[4];
#pragma unroll
      for (int i = 0; i < 4; ++i) af[i]  = frag_ld(ldsA, wm + i * 16 + (lane & 15), kk, lane);
#pragma unroll
      for (int i = 0; i < 4; ++i) bfr[i] = frag_ld(ldsB, wn + i * 16 + (lane & 15), kk, lane);
#pragma unroll
      for (int m = 0; m < 4; ++m)
#pragma unroll
        for (int n = 0; n < 4; ++n)
          acc2[m][n] = __builtin_amdgcn_mfma_f32_16x16x32_bf16(af[m], bfr[n], acc2[m][n], 0, 0, 0);
    }
    __syncthreads();
  }
  // write sin||cos
#pragma unroll
  for (int m = 0; m < 4; ++m){
    const int r0 = wm + m * 16 + ((lane >> 4) << 2);
#pragma unroll
    for (int n = 0; n < 4; ++n){
      const int f = wn + n * 16 + (lane & 15);
      if (sect == 0){
#pragma unroll
        for (int j = 0; j < 4; ++j){
          float sv, cv; __sincosf(acc2[m][n][j], &sv, &cv);
          size_t base = ((size_t)bh * 4096 + s0 + r0 + j) * 256;
          Qf[base + f]       = f2b(sv);
          Qf[base + 128 + f] = f2b(cv);
        }
      } else {
        u16x4 ps, pc;
#pragma unroll
        for (int j = 0; j < 4; ++j){
          float sv, cv; __sincosf(acc2[m][n][j], &sv, &cv);
          ps[j] = f2b(sv); pc[j] = f2b(cv);
        }
        size_t sb = (size_t)s0 + r0;
        *(u16x4*)&KfT[((size_t)bh * 256 + f) * 4096 + sb]       = ps;
        *(u16x4*)&KfT[((size_t)bh * 256 + 128 + f) * 4096 + sb] = pc;
      }
    }
  }
}

// ---- K3: KV = Kf^T V (+Ksum via ones row). grid (2 mtiles, 32 bh, 4 ksplit) ----
__global__ __launch_bounds__(256, 2)
void k_kv(const u16* __restrict__ KfT, const u16* __restrict__ VT, float* __restrict__ part){
  __shared__ u16 ldsA[128 * 64];
  __shared__ u16 ldsB[NKV * 64];
  const int mtile = blockIdx.x, bh = blockIdx.y, ks = blockIdx.z;
  const u16* Ag = KfT + ((size_t)bh * 256 + mtile * 128) * 4096 + ks * 1024;
  const u16* Bg = VT + (size_t)bh * NKV * 4096 + ks * 1024;
  f32x4 acc[2][9];
#pragma unroll
  for (int m = 0; m < 2; ++m)
#pragma unroll
    for (int n = 0; n < 9; ++n) acc[m][n] = f32x4{0.f, 0.f, 0.f, 0.f};
  core41(Ag, 4096, Bg, 4096, 16, ldsA, ldsB, acc);

  const int tid = threadIdx.x, lane = tid & 63, w = tid >> 6;
#pragma unroll
  for (int m = 0; m < 2; ++m){
    const int mr = mtile * 128 + w * 32 + m * 16 + ((lane >> 4) << 2);
#pragma unroll
    for (int n = 0; n < 9; ++n){
      const int nn = n * 16 + (lane & 15);
      *(f32x4*)&part[(((size_t)ks * 32 + bh) * NKV + nn) * 256 + mr] = acc[m][n];
    }
  }
}

__global__ void k_kvred(const float* __restrict__ part, u16* __restrict__ KVT){
  const int total = 32 * NKV * 256;
  int idx = blockIdx.x * blockDim.x + threadIdx.x;
  if (idx >= total) return;
  float v = 0.f;
#pragma unroll
  for (int p = 0; p < 4; ++p) v += part[(size_t)p * total + idx];
  KVT[idx] = f2b(v);
}

// ---- K5: out = (Qf @ KV) / denom. grid (32 mtiles, 32 bh) ----
__global__ __launch_bounds__(256, 2)
void k_attn(const u16* __restrict__ Qf, const u16* __restrict__ KVT, u16* __restrict__ att){
  __shared__ u16 ldsA[128 * 64];
  __shared__ u16 ldsB[NKV * 64];
  const int mtile = blockIdx.x, bh = blockIdx.y;
  const u16* Ag = Qf + ((size_t)bh * 4096 + mtile * 128) * 256;
  const u16* Bg = KVT + (size_t)bh * NKV * 256;
  f32x4 acc[2][9];
#pragma unroll
  for (int m = 0; m < 2; ++m)
#pragma unroll
    for (int n = 0; n < 9; ++n) acc[m][n] = f32x4{0.f, 0.f, 0.f, 0.f};
  core41(Ag, 256, Bg, 256, 4, ldsA, ldsB, acc);

  const int tid = threadIdx.x, lane = tid & 63, w = tid >> 6;
  const int b = bh >> 3, h = bh & 7;
#pragma unroll
  for (int m = 0; m < 2; ++m){
    const int r0 = mtile * 128 + w * 32 + m * 16 + ((lane >> 4) << 2);
    float rden[4];
#pragma unroll
    for (int j = 0; j < 4; ++j){
      float d = __shfl(acc[m][8][j], lane & 48, 64);
      rden[j] = 1.f / (d + 1e-6f);
    }
#pragma unroll
    for (int n = 0; n < 8; ++n){
      const int dcol = n * 16 + (lane & 15);
#pragma unroll
      for (int j = 0; j < 4; ++j)
        att[((size_t)b * 4096 + r0 + j) * 1024 + h * 128 + dcol] = f2b(acc[m][n][j] * rden[j]);
    }
  }
}

// ---- K6: final projection. grid (128, 8) ----
__global__ __launch_bounds__(256, 2)
void k_out(const u16* __restrict__ att, const u16* __restrict__ WoT,
           const float* __restrict__ bo, float* __restrict__ out){
  __shared__ u16 ldsA[128 * 64];
  __shared__ u16 ldsB[128 * 64];
  const int mtile = blockIdx.x, ntile = blockIdx.y;
  const u16* Ag = att + (size_t)mtile * 128 * 1024;
  const u16* Bg = WoT + (size_t)ntile * 128 * 1024;
  f32x4 acc[4][4];
#pragma unroll
  for (int m = 0; m < 4; ++m)
#pragma unroll
    for (int n = 0; n < 4; ++n) acc[m][n] = f32x4{0.f, 0.f, 0.f, 0.f};
  core22(Ag, 1024, Bg, 1024, 16, ldsA, ldsB, acc);

  const int tid = threadIdx.x, lane = tid & 63, w = tid >> 6;
  const int wm = (w >> 1) * 64, wn = (w & 1) * 64;
#pragma unroll
  for (int m = 0; m < 4; ++m){
    const int rg = mtile * 128 + wm + m * 16 + ((lane >> 4) << 2);
#pragma unroll
    for (int n = 0; n < 4; ++n){
      const int c = ntile * 128 + wn + n * 16 + (lane & 15);
      const float bc = bo[c];
#pragma unroll
      for (int j = 0; j < 4; ++j)
        out[(size_t)(rg + j) * 1024 + c] = acc[m][n][j] + bc;
    }
  }
}

extern "C" void kernel_launch(void* const* d_in, const int* in_sizes, int n_in,
                              void* d_out, int out_size, void* d_ws, size_t ws_size,
                              hipStream_t stream){
  const float* x  = (const float*)d_in[0];
  const float* Wq = (const float*)d_in[1];
  const float* bq = (const float*)d_in[2];
  const float* Wk = (const float*)d_in[3];
  const float* bk = (const float*)d_in[4];
  const float* Wv = (const float*)d_in[5];
  const float* bv = (const float*)d_in[6];
  const float* Wo = (const float*)d_in[7];
  const float* bo = (const float*)d_in[8];
  const float* om = (const float*)d_in[9];
  float* out = (float*)d_out;
  char* ws = (char*)d_ws;

  // layout (bytes). Region 0 timeline: xb (until k_qkv) -> part (k_kv/k_kvred)
  // -> att (k_attn/k_out). KfT no longer aliases xb (fused k_qkv reads xb
  // while writing KfT).
  const size_t OFF_XB  = 0;             // 32 MiB : xb  [16384][1024] bf16
  const size_t OFF_PART= 0;             // 18 MiB : part [4][32][144][256] f32 (alias)
  const size_t OFF_ATT = 0;             // 32 MiB : att [16384][1024] bf16 (alias)
  const size_t OFF_KFT = 33554432;      // 64 MiB : KfT [32][256][4096] bf16
  const size_t OFF_QF  = 100663296;     // 64 MiB : Qf  [32][4096][256] bf16
  const size_t OFF_VT  = 167772160;     // 36 MiB : VT  [32][144][4096] bf16
  const size_t OFF_KVT = 205520896;     // 2.25MiB: KVT [32][144][256] bf16
  const size_t OFF_WQT = 207880192;     // 4 x 2 MiB + 32 KiB weights
  const size_t OFF_WKT = OFF_WQT + 2097152;
  const size_t OFF_WVT = OFF_WKT + 2097152;
  const size_t OFF_WOT = OFF_WVT + 2097152;
  const size_t OFF_WT  = OFF_WOT + 2097152;
  const size_t NEEDED  = OFF_WT + 32768;
  if (ws_size < NEEDED) return;  // insufficient scratch: fail loudly

  u16* xb  = (u16*)(ws + OFF_XB);
  u16* WqT = (u16*)(ws + OFF_WQT);
  u16* WkT = (u16*)(ws + OFF_WKT);
  u16* WvT = (u16*)(ws + OFF_WVT);
  u16* WoT = (u16*)(ws + OFF_WOT);
  u16* wT  = (u16*)(ws + OFF_WT);
  u16* VT  = (u16*)(ws + OFF_VT);
  u16* Qf  = (u16*)(ws + OFF_QF);
  u16* KfT = (u16*)(ws + OFF_KFT);
  float* part = (float*)(ws + OFF_PART);
  u16* KVT = (u16*)(ws + OFF_KVT);
  u16* att = (u16*)(ws + OFF_ATT);

  k_cast2<<<dim3(2304), dim3(256), 0, stream>>>(x, xb, VT);
  k_tc4<<<dim3(16, 16, 4), dim3(256), 0, stream>>>(Wq, Wk, Wv, Wo, WqT, WkT, WvT, WoT);
  k_tc<<<dim3(2, 2), dim3(256), 0, stream>>>(om, wT, 128, 128);

  k_qkv<<<dim3(128, 24), dim3(256), 0, stream>>>(xb, WqT, WkT, WvT, bq, bk, bv, wT, Qf, KfT, VT);
  k_kv<<<dim3(2, 32, 4), dim3(256), 0, stream>>>(KfT, VT, part);
  k_kvred<<<dim3(32 * NKV * 256 / 256), dim3(256), 0, stream>>>(part, KVT);
  k_attn<<<dim3(32, 32), dim3(256), 0, stream>>>(Qf, KVT, att);
  k_out<<<dim3(128, 8), dim3(256), 0, stream>>>(att, WoT, bo, out);
}

// Round 5
// 305.715 us; speedup vs baseline: 1.0967x; 1.0967x over previous
//
#include <hip/hip_runtime.h>

typedef unsigned short u16;
typedef unsigned int u32;
typedef __attribute__((ext_vector_type(8))) short bf16x8;
typedef __attribute__((ext_vector_type(4))) float f32x4;
typedef __attribute__((ext_vector_type(4))) unsigned short u16x4;

#define NKV 144   // 128 V-dims + 1 ones-row (Ksum) + 15 zero pad (9 MFMA n-frags)

__device__ __forceinline__ u16 f2b(float f){
  u32 i = __float_as_uint(f);
  u32 r = (i + 0x7FFFu + ((i >> 16) & 1u)) >> 16;
  return (u16)r;
}

__device__ __forceinline__ void cp16(const void* g, void* l){
  __builtin_amdgcn_global_load_lds(
      (__attribute__((address_space(1))) void*)(const_cast<void*>(g)),
      (__attribute__((address_space(3))) void*)(l), 16, 0, 0);
}

// Stage rows x 64 bf16 (rows*128 bytes) into LDS. Linear LDS dest (required by
// global_load_lds); XOR 16B-chunk swizzle applied on the GLOBAL source so that
// swizzled reads below are conflict-light (2-way max).
__device__ __forceinline__ void stage_tile(const u16* g, int stride_el, int rows,
                                           u16* lds, int tid){
  const char* gc = (const char*)g;
  char* lc = (char*)lds;
  const int total = rows * 128;
  for (int off = tid * 16; off < total; off += 4096){
    int row = off >> 7;
    int chunk = (off >> 4) & 7;
    int gchunk = chunk ^ (row & 7);
    cp16(gc + (size_t)row * (size_t)(stride_el * 2) + gchunk * 16, lc + off);
  }
}

// Fragment read: logical (row, k-chunk) -> swizzled physical chunk.
__device__ __forceinline__ bf16x8 frag_ld(const u16* lds, int row, int kk, int lane){
  int chunk = (kk >> 3) + (lane >> 4);
  int pc = chunk ^ (row & 7);
  return *(const bf16x8*)(lds + row * 64 + pc * 8);
}

// ---- core A: 4 waves in 2x2, each wave 64x64 (4x4 frags), BM=BN=128, BK=64 ----
__device__ __forceinline__ void core22(const u16* Ag, int As, const u16* Bg, int Bs,
                                       int ksteps, u16* ldsA, u16* ldsB,
                                       f32x4 (&acc)[4][4]){
  const int tid = threadIdx.x, lane = tid & 63, w = tid >> 6;
  const int wm = (w >> 1) * 64, wn = (w & 1) * 64;
  for (int t = 0; t < ksteps; ++t){
    stage_tile(Ag + t * 64, As, 128, ldsA, tid);
    stage_tile(Bg + t * 64, Bs, 128, ldsB, tid);
    __syncthreads();
#pragma unroll
    for (int kk = 0; kk < 64; kk += 32){
      bf16x8 af[4], bfr[4];
#pragma unroll
      for (int i = 0; i < 4; ++i) af[i]  = frag_ld(ldsA, wm + i * 16 + (lane & 15), kk, lane);
#pragma unroll
      for (int i = 0; i < 4; ++i) bfr[i] = frag_ld(ldsB, wn + i * 16 + (lane & 15), kk, lane);
#pragma unroll
      for (int m = 0; m < 4; ++m)
#pragma unroll
        for (int n = 0; n < 4; ++n)
          acc[m][n] = __builtin_amdgcn_mfma_f32_16x16x32_bf16(af[m], bfr[n], acc[m][n], 0, 0, 0);
    }
    __syncthreads();
  }
}

// ---- core B: 4 waves m-stacked, each wave 32x144 (2x9 frags), BM=128, BN=144 ----
__device__ __forceinline__ void core41(const u16* Ag, int As, const u16* Bg, int Bs,
                                       int ksteps, u16* ldsA, u16* ldsB,
                                       f32x4 (&acc)[2][9]){
  const int tid = threadIdx.x, lane = tid & 63, w = tid >> 6;
  const int wm = w * 32;
  for (int t = 0; t < ksteps; ++t){
    stage_tile(Ag + t * 64, As, 128, ldsA, tid);
    stage_tile(Bg + t * 64, Bs, NKV, ldsB, tid);
    __syncthreads();
#pragma unroll
    for (int kk = 0; kk < 64; kk += 32){
      bf16x8 af[2], bfr[9];
#pragma unroll
      for (int i = 0; i < 2; ++i) af[i]  = frag_ld(ldsA, wm + i * 16 + (lane & 15), kk, lane);
#pragma unroll
      for (int i = 0; i < 9; ++i) bfr[i] = frag_ld(ldsB, i * 16 + (lane & 15), kk, lane);
#pragma unroll
      for (int m = 0; m < 2; ++m)
#pragma unroll
        for (int n = 0; n < 9; ++n)
          acc[m][n] = __builtin_amdgcn_mfma_f32_16x16x32_bf16(af[m], bfr[n], acc[m][n], 0, 0, 0);
    }
    __syncthreads();
  }
}

// ---- prep: x cast (blocks 0..2047) + VT pad-row init (blocks 2048..2303) ----
__global__ void k_cast2(const float* __restrict__ src, u16* __restrict__ dst,
                        u16* __restrict__ VT){
  if (blockIdx.x < 2048){
    const int n4 = 16384 * 1024 / 4;
    const int stride = 2048 * 256;
    for (int i = blockIdx.x * 256 + threadIdx.x; i < n4; i += stride){
      float4 v = ((const float4*)src)[i];
      u16x4 o; o[0] = f2b(v.x); o[1] = f2b(v.y); o[2] = f2b(v.z); o[3] = f2b(v.w);
      ((u16x4*)dst)[i] = o;
    }
  } else {
    const int total = 32 * 16 * 4096 / 4;
    const int stride = 256 * 256;
    for (int i = (blockIdx.x - 2048) * 256 + threadIdx.x; i < total; i += stride){
      int idx = i * 4;
      int s   = idx & 4095;
      int rem = idx >> 12;
      int row = 128 + (rem & 15);
      int bh  = rem >> 4;
      u16 val = (row == 128) ? (u16)0x3F80 : (u16)0;
      u16x4 o = {val, val, val, val};
      *(u16x4*)&VT[((size_t)bh * NKV + row) * 4096 + s] = o;
    }
  }
}

// 2 weight transposes (Wv, Wo) in one launch: grid (16,16,2)
__global__ void k_tc2(const float* __restrict__ Wv, const float* __restrict__ Wo,
                      u16* __restrict__ WvT, u16* __restrict__ WoT){
  __shared__ float t[64][65];
  const float* src = blockIdx.z ? Wo : Wv;
  u16* dst = blockIdx.z ? WoT : WvT;
  const int c0 = blockIdx.x * 64, r0 = blockIdx.y * 64;
  const int tid = threadIdx.x;
  for (int i = tid; i < 4096; i += 256){
    int r = i >> 6, c = i & 63;
    t[r][c] = src[(size_t)(r0 + r) * 1024 + c0 + c];
  }
  __syncthreads();
  for (int i = tid; i < 4096; i += 256){
    int r = i >> 6, c = i & 63;
    dst[(size_t)(c0 + r) * 1024 + r0 + c] = f2b(t[c][r]);
  }
}

// ---- fused feature weights: WqphiT[h*128+f][d] = sum_c Wq[d][h*128+c]*om[c][f]
//      bphi[z*1024 + h*128+f] = sum_c b[h*128+c]*om[c][f]
// grid (128, 2): blockIdx.x -> (h = bx>>4, f0 = (bx&15)*8); z: 0=Q, 1=K
__global__ void k_wfuse(const float* __restrict__ Wq, const float* __restrict__ bq,
                        const float* __restrict__ Wk, const float* __restrict__ bk,
                        const float* __restrict__ om, u16* __restrict__ WqpT,
                        u16* __restrict__ WkpT, float* __restrict__ bphi){
  const int z = blockIdx.y;
  const float* W  = z ? Wk : Wq;
  const float* bb = z ? bk : bq;
  u16* WT = z ? WkpT : WqpT;
  const int h  = blockIdx.x >> 4;
  const int f0 = (blockIdx.x & 15) * 8;
  const int t  = threadIdx.x;
  __shared__ float oc[128][8];
  if (t < 128){
#pragma unroll
    for (int ff = 0; ff < 8; ++ff) oc[t][ff] = om[t * 128 + f0 + ff];
  }
  __syncthreads();
  for (int rep = 0; rep < 4; ++rep){
    const int d = rep * 256 + t;
    const float* wrow = W + (size_t)d * 1024 + h * 128;
    float s[8] = {0.f, 0.f, 0.f, 0.f, 0.f, 0.f, 0.f, 0.f};
    for (int c = 0; c < 128; ++c){
      const float wv = wrow[c];
#pragma unroll
      for (int ff = 0; ff < 8; ++ff) s[ff] += wv * oc[c][ff];
    }
#pragma unroll
    for (int ff = 0; ff < 8; ++ff)
      WT[(size_t)(h * 128 + f0 + ff) * 1024 + d] = f2b(s[ff]);
  }
  if (t < 8){
    float s = 0.f;
    const float* bp = bb + h * 128;
    for (int c = 0; c < 128; ++c) s += bp[c] * oc[c][t];
    bphi[z * 1024 + h * 128 + f0 + t] = s;
  }
}

// ---- K2: fused-weight QKV. grid (128 mtiles, 24 ntiles); ntile -> (sect,h) ----
// sect 0: zp = x@Wqphi + bqphi -> sincos -> Qf [bh][s][256]
// sect 1: zp = x@Wkphi + bkphi -> sincos -> KfT [bh][f][4096] (transposed)
// sect 2: V = x@Wv + bv -> VT [bh][d][4096] (transposed)
__global__ __launch_bounds__(256, 2)
void k_qkv(const u16* __restrict__ xb, const u16* __restrict__ WqpT,
           const u16* __restrict__ WkpT, const u16* __restrict__ WvT,
           const float* __restrict__ bphi, const float* __restrict__ bv,
           u16* __restrict__ Qf, u16* __restrict__ KfT, u16* __restrict__ VT){
  __shared__ u16 ldsA[128 * 64];
  __shared__ u16 ldsB[128 * 64];
  const int mtile = blockIdx.x, ntile = blockIdx.y;
  const int sect = ntile >> 3, h = ntile & 7;
  const u16* Ag = xb + (size_t)mtile * 128 * 1024;
  const u16* WT = sect == 0 ? WqpT : (sect == 1 ? WkpT : WvT);
  const u16* Bg = WT + (size_t)h * 128 * 1024;
  f32x4 acc[4][4];
#pragma unroll
  for (int m = 0; m < 4; ++m)
#pragma unroll
    for (int n = 0; n < 4; ++n) acc[m][n] = f32x4{0.f, 0.f, 0.f, 0.f};
  core22(Ag, 1024, Bg, 1024, 16, ldsA, ldsB, acc);

  const int tid = threadIdx.x, lane = tid & 63, w = tid >> 6;
  const int wm = (w >> 1) * 64, wn = (w & 1) * 64;
  const int b  = (mtile * 128) >> 12;
  const int s0 = (mtile * 128) & 4095;
  const int bh = b * 8 + h;

  if (sect == 2){
    const float* bias = bv + h * 128;
#pragma unroll
    for (int m = 0; m < 4; ++m){
      const int r0 = wm + m * 16 + ((lane >> 4) << 2);
#pragma unroll
      for (int n = 0; n < 4; ++n){
        const int col = wn + n * 16 + (lane & 15);
        const float bc = bias[col];
        u16x4 pk;
#pragma unroll
        for (int j = 0; j < 4; ++j) pk[j] = f2b(acc[m][n][j] + bc);
        *(u16x4*)&VT[((size_t)bh * NKV + col) * 4096 + s0 + r0] = pk;
      }
    }
    return;
  }

  const float* bph = bphi + sect * 1024 + h * 128;
#pragma unroll
  for (int m = 0; m < 4; ++m){
    const int r0 = wm + m * 16 + ((lane >> 4) << 2);
#pragma unroll
    for (int n = 0; n < 4; ++n){
      const int f = wn + n * 16 + (lane & 15);
      const float bc = bph[f];
      if (sect == 0){
#pragma unroll
        for (int j = 0; j < 4; ++j){
          float sv, cv; __sincosf(acc[m][n][j] + bc, &sv, &cv);
          size_t base = ((size_t)bh * 4096 + s0 + r0 + j) * 256;
          Qf[base + f]       = f2b(sv);
          Qf[base + 128 + f] = f2b(cv);
        }
      } else {
        u16x4 ps, pc;
#pragma unroll
        for (int j = 0; j < 4; ++j){
          float sv, cv; __sincosf(acc[m][n][j] + bc, &sv, &cv);
          ps[j] = f2b(sv); pc[j] = f2b(cv);
        }
        size_t sb = (size_t)s0 + r0;
        *(u16x4*)&KfT[((size_t)bh * 256 + f) * 4096 + sb]       = ps;
        *(u16x4*)&KfT[((size_t)bh * 256 + 128 + f) * 4096 + sb] = pc;
      }
    }
  }
}

// ---- K3: KV = Kf^T V (+Ksum via ones row). grid (2 mtiles, 32 bh, 4 ksplit) ----
__global__ __launch_bounds__(256, 2)
void k_kv(const u16* __restrict__ KfT, const u16* __restrict__ VT, float* __restrict__ part){
  __shared__ u16 ldsA[128 * 64];
  __shared__ u16 ldsB[NKV * 64];
  const int mtile = blockIdx.x, bh = blockIdx.y, ks = blockIdx.z;
  const u16* Ag = KfT + ((size_t)bh * 256 + mtile * 128) * 4096 + ks * 1024;
  const u16* Bg = VT + (size_t)bh * NKV * 4096 + ks * 1024;
  f32x4 acc[2][9];
#pragma unroll
  for (int m = 0; m < 2; ++m)
#pragma unroll
    for (int n = 0; n < 9; ++n) acc[m][n] = f32x4{0.f, 0.f, 0.f, 0.f};
  core41(Ag, 4096, Bg, 4096, 16, ldsA, ldsB, acc);

  const int tid = threadIdx.x, lane = tid & 63, w = tid >> 6;
#pragma unroll
  for (int m = 0; m < 2; ++m){
    const int mr = mtile * 128 + w * 32 + m * 16 + ((lane >> 4) << 2);
#pragma unroll
    for (int n = 0; n < 9; ++n){
      const int nn = n * 16 + (lane & 15);
      *(f32x4*)&part[(((size_t)ks * 32 + bh) * NKV + nn) * 256 + mr] = acc[m][n];
    }
  }
}

__global__ void k_kvred(const float* __restrict__ part, u16* __restrict__ KVT){
  const int total = 32 * NKV * 256;
  int idx = blockIdx.x * blockDim.x + threadIdx.x;
  if (idx >= total) return;
  float v = 0.f;
#pragma unroll
  for (int p = 0; p < 4; ++p) v += part[(size_t)p * total + idx];
  KVT[idx] = f2b(v);
}

// ---- K5: out = (Qf @ KV) / denom. grid (32 mtiles, 32 bh) ----
__global__ __launch_bounds__(256, 2)
void k_attn(const u16* __restrict__ Qf, const u16* __restrict__ KVT, u16* __restrict__ att){
  __shared__ u16 ldsA[128 * 64];
  __shared__ u16 ldsB[NKV * 64];
  const int mtile = blockIdx.x, bh = blockIdx.y;
  const u16* Ag = Qf + ((size_t)bh * 4096 + mtile * 128) * 256;
  const u16* Bg = KVT + (size_t)bh * NKV * 256;
  f32x4 acc[2][9];
#pragma unroll
  for (int m = 0; m < 2; ++m)
#pragma unroll
    for (int n = 0; n < 9; ++n) acc[m][n] = f32x4{0.f, 0.f, 0.f, 0.f};
  core41(Ag, 256, Bg, 256, 4, ldsA, ldsB, acc);

  const int tid = threadIdx.x, lane = tid & 63, w = tid >> 6;
  const int b = bh >> 3, h = bh & 7;
#pragma unroll
  for (int m = 0; m < 2; ++m){
    const int r0 = mtile * 128 + w * 32 + m * 16 + ((lane >> 4) << 2);
    float rden[4];
#pragma unroll
    for (int j = 0; j < 4; ++j){
      float d = __shfl(acc[m][8][j], lane & 48, 64);
      rden[j] = 1.f / (d + 1e-6f);
    }
#pragma unroll
    for (int n = 0; n < 8; ++n){
      const int dcol = n * 16 + (lane & 15);
#pragma unroll
      for (int j = 0; j < 4; ++j)
        att[((size_t)b * 4096 + r0 + j) * 1024 + h * 128 + dcol] = f2b(acc[m][n][j] * rden[j]);
    }
  }
}

// ---- K6: final projection. grid (128, 8) ----
__global__ __launch_bounds__(256, 2)
void k_out(const u16* __restrict__ att, const u16* __restrict__ WoT,
           const float* __restrict__ bo, float* __restrict__ out){
  __shared__ u16 ldsA[128 * 64];
  __shared__ u16 ldsB[128 * 64];
  const int mtile = blockIdx.x, ntile = blockIdx.y;
  const u16* Ag = att + (size_t)mtile * 128 * 1024;
  const u16* Bg = WoT + (size_t)ntile * 128 * 1024;
  f32x4 acc[4][4];
#pragma unroll
  for (int m = 0; m < 4; ++m)
#pragma unroll
    for (int n = 0; n < 4; ++n) acc[m][n] = f32x4{0.f, 0.f, 0.f, 0.f};
  core22(Ag, 1024, Bg, 1024, 16, ldsA, ldsB, acc);

  const int tid = threadIdx.x, lane = tid & 63, w = tid >> 6;
  const int wm = (w >> 1) * 64, wn = (w & 1) * 64;
#pragma unroll
  for (int m = 0; m < 4; ++m){
    const int rg = mtile * 128 + wm + m * 16 + ((lane >> 4) << 2);
#pragma unroll
    for (int n = 0; n < 4; ++n){
      const int c = ntile * 128 + wn + n * 16 + (lane & 15);
      const float bc = bo[c];
#pragma unroll
      for (int j = 0; j < 4; ++j)
        out[(size_t)(rg + j) * 1024 + c] = acc[m][n][j] + bc;
    }
  }
}

extern "C" void kernel_launch(void* const* d_in, const int* in_sizes, int n_in,
                              void* d_out, int out_size, void* d_ws, size_t ws_size,
                              hipStream_t stream){
  const float* x  = (const float*)d_in[0];
  const float* Wq = (const float*)d_in[1];
  const float* bq = (const float*)d_in[2];
  const float* Wk = (const float*)d_in[3];
  const float* bk = (const float*)d_in[4];
  const float* Wv = (const float*)d_in[5];
  const float* bv = (const float*)d_in[6];
  const float* Wo = (const float*)d_in[7];
  const float* bo = (const float*)d_in[8];
  const float* om = (const float*)d_in[9];
  float* out = (float*)d_out;
  char* ws = (char*)d_ws;

  // layout (bytes). Region 0 timeline: xb (until k_qkv done) -> part (k_kv,
  // k_kvred) -> att (k_attn, k_out). No QKV buffer (phi folded into weights).
  const size_t OFF_XB  = 0;             // 32 MiB : xb  [16384][1024] bf16
  const size_t OFF_PART= 0;             // 19 MiB : part [4][32][144][256] f32 (alias)
  const size_t OFF_ATT = 0;             // 32 MiB : att [16384][1024] bf16 (alias)
  const size_t OFF_KFT = 33554432;      // 64 MiB : KfT [32][256][4096] bf16
  const size_t OFF_QF  = 100663296;     // 64 MiB : Qf  [32][4096][256] bf16
  const size_t OFF_VT  = 167772160;     // 36 MiB : VT  [32][144][4096] bf16
  const size_t OFF_KVT = 205520896;     // 2.25MiB: KVT [32][144][256] bf16
  const size_t OFF_WQP = 207880192;     // 2 MiB : WqphiT [1024][1024] bf16
  const size_t OFF_WKP = OFF_WQP + 2097152;
  const size_t OFF_WVT = OFF_WKP + 2097152;
  const size_t OFF_WOT = OFF_WVT + 2097152;
  const size_t OFF_BPH = OFF_WOT + 2097152;  // 8 KiB f32 bphi[2][1024]
  const size_t NEEDED  = OFF_BPH + 8192;
  if (ws_size < NEEDED) return;  // insufficient scratch: fail loudly

  u16* xb   = (u16*)(ws + OFF_XB);
  u16* WqpT = (u16*)(ws + OFF_WQP);
  u16* WkpT = (u16*)(ws + OFF_WKP);
  u16* WvT  = (u16*)(ws + OFF_WVT);
  u16* WoT  = (u16*)(ws + OFF_WOT);
  float* bphi = (float*)(ws + OFF_BPH);
  u16* VT   = (u16*)(ws + OFF_VT);
  u16* Qf   = (u16*)(ws + OFF_QF);
  u16* KfT  = (u16*)(ws + OFF_KFT);
  float* part = (float*)(ws + OFF_PART);
  u16* KVT  = (u16*)(ws + OFF_KVT);
  u16* att  = (u16*)(ws + OFF_ATT);

  k_cast2<<<dim3(2304), dim3(256), 0, stream>>>(x, xb, VT);
  k_tc2<<<dim3(16, 16, 2), dim3(256), 0, stream>>>(Wv, Wo, WvT, WoT);
  k_wfuse<<<dim3(128, 2), dim3(256), 0, stream>>>(Wq, bq, Wk, bk, om, WqpT, WkpT, bphi);

  k_qkv<<<dim3(128, 24), dim3(256), 0, stream>>>(xb, WqpT, WkpT, WvT, bphi, bv, Qf, KfT, VT);
  k_kv<<<dim3(2, 32, 4), dim3(256), 0, stream>>>(KfT, VT, part);
  k_kvred<<<dim3(32 * NKV * 256 / 256), dim3(256), 0, stream>>>(part, KVT);
  k_attn<<<dim3(32, 32), dim3(256), 0, stream>>>(Qf, KVT, att);
  k_out<<<dim3(128, 8), dim3(256), 0, stream>>>(att, WoT, bo, out);
}